// Round 7
// baseline (763.735 us; speedup 1.0000x reference)
//
#include <hip/hip_runtime.h>

namespace {

typedef float v2f __attribute__((ext_vector_type(2)));

constexpr int T_SEQ = 2048;
constexpr int B_SZ  = 512;
constexpr int C_IN  = 8;
constexpr int H_SZ  = 20;
constexpr int P_LEN = 32;                 // steps per phase (barrier period)
constexpr int N_PH  = T_SEQ / P_LEN;      // 64 phases
constexpr int RING  = 2 * P_LEN;          // 64-slot h0 handoff ring
constexpr float LOG2E = 1.44269504088896340736f;

__device__ __forceinline__ int rl_i(float v, int lane) {
  return __builtin_amdgcn_readlane(__float_as_int(v), lane);
}

template<int S>
__device__ __forceinline__ float quad_bcast(float v) {
  return __int_as_float(__builtin_amdgcn_update_dpp(
      __float_as_int(v), __float_as_int(v), S * 0x55, 0xF, 0xF, true));
}

__device__ __forceinline__ v2f fma2(v2f a, v2f b, v2f c) {
  return __builtin_elementwise_fma(a, b, c);   // v_pk_fma_f32, all-VGPR
}
__device__ __forceinline__ v2f zero2() { v2f r; r.x = 0.f; r.y = 0.f; return r; }

// Weights/bias pre-scaled by cm, so dot result G is already a*cm:
// act = rcp(1+exp2(G))*am + ad   (sigmoid for g!=2, tanh for g==2)
__device__ __forceinline__ float act_s(float G, float am, float ad) {
  float e = __builtin_amdgcn_exp2f(G);
  float s = __builtin_amdgcn_rcpf(1.0f + e);
  return __fmaf_rn(s, am, ad);
}

__device__ __forceinline__ float fast_tanh(float a) {
  float e = __builtin_amdgcn_exp2f(a * (-2.0f * LOG2E));
  float s = __builtin_amdgcn_rcpf(1.0f + e);
  return __fmaf_rn(s, 2.0f, -1.0f);
}

// h[k] broadcast from quad-distributed regs -> SGPR int (set1 at lanes 4k for
// k<16; set2 value for k=16..19 replicated, take lane 4*(k-16)).
#define H_RL(ha, hb, k) (((k) < 16) ? rl_i((ha), 4 * (k)) : rl_i((hb), 4 * ((k) - 16)))

__global__ __attribute__((amdgpu_flat_work_group_size(128, 128),
                          amdgpu_waves_per_eu(1, 1)))
void lstm2_hy(const float* __restrict__ x,
              const float* __restrict__ Wih0, const float* __restrict__ Whh0,
              const float* __restrict__ bih0, const float* __restrict__ bhh0,
              const float* __restrict__ Wih1, const float* __restrict__ Whh1,
              const float* __restrict__ bih1, const float* __restrict__ bhh1,
              float* __restrict__ out)
{
  __shared__ __align__(16) float hbuf[RING][H_SZ];       // h0 handoff ring
  __shared__ __align__(16) float xbuf[2][P_LEN * C_IN];  // x staging

  const int tid = threadIdx.x;
  const int wv  = tid >> 6;          // 0 = layer-0 wave, 1 = layer-1 wave
  const int l   = tid & 63;
  const int b   = blockIdx.x;
  const int k1  = l >> 2;            // 0..15
  const int g   = l & 3;             // gate slot: 0=i 1=f 2=g 3=o
  const int k2  = 16 + (k1 & 3);     // 16..19 (replicated)
  const int j1  = g * H_SZ + k1;
  const int j2  = g * H_SZ + k2;

  const bool  isg = (g == 2);
  const float cm  = isg ? (-2.0f * LOG2E) : (-LOG2E);
  const float am  = isg ?  2.0f : 1.0f;
  const float ad  = isg ? -1.0f : 0.0f;

  if (wv == 0) {
    // ================= layer-0 producer wave =================
    float whs1[H_SZ], whs2[H_SZ];      // Whh0 rows j1/j2, prescaled by cm
    v2f   wxp1[C_IN / 2], wxp2[C_IN / 2];  // Wih0 rows, k-paired, prescaled
#pragma unroll
    for (int k = 0; k < H_SZ; ++k) {
      whs1[k] = Whh0[j1 * H_SZ + k] * cm;
      whs2[k] = Whh0[j2 * H_SZ + k] * cm;
    }
#pragma unroll
    for (int t = 0; t < C_IN / 2; ++t) {
      wxp1[t].x = Wih0[j1 * C_IN + 2 * t] * cm;
      wxp1[t].y = Wih0[j1 * C_IN + 2 * t + 1] * cm;
      wxp2[t].x = Wih0[j2 * C_IN + 2 * t] * cm;
      wxp2[t].y = Wih0[j2 * C_IN + 2 * t + 1] * cm;
    }
    const float bs1 = (bih0[j1] + bhh0[j1]) * cm;
    const float bs2 = (bih0[j2] + bhh0[j2]) * cm;

    float ha = 0.f, hb = 0.f, ca = 0.f, cb = 0.f;

    // x stream: lane l covers phase element e = l + 64u (u=0..3);
    // t = 32p + (l>>3) + 8u, ch = l&7.
    const float* xl = x + (size_t)(l >> 3) * (B_SZ * C_IN)
                        + (size_t)b * C_IN + (l & 7);
    const size_t ustr  = (size_t)8 * B_SZ * C_IN;
    const size_t phstr = (size_t)P_LEN * B_SZ * C_IN;
    {   // phase 0 committed now
      float a0 = xl[0], a1 = xl[ustr], a2 = xl[2 * ustr], a3 = xl[3 * ustr];
      xbuf[0][l] = a0; xbuf[0][64 + l] = a1;
      xbuf[0][128 + l] = a2; xbuf[0][192 + l] = a3;
    }
    float xr0 = xl[phstr], xr1 = xl[phstr + ustr],
          xr2 = xl[phstr + 2 * ustr], xr3 = xl[phstr + 3 * ustr];

    for (int p = 0; p <= N_PH; ++p) {
      if (p < N_PH) {
        const int buf = p & 1;
        // Commit next phase's x EARLY, then issue p+2 loads so they have a
        // full phase in flight before the barrier's vmcnt(0) drain.
        if (p + 1 < N_PH) {
          const int nb = (p + 1) & 1;
          xbuf[nb][l] = xr0; xbuf[nb][64 + l] = xr1;
          xbuf[nb][128 + l] = xr2; xbuf[nb][192 + l] = xr3;
        }
        if (p + 2 < N_PH) {
          const size_t o = (size_t)(p + 2) * phstr;
          xr0 = xl[o]; xr1 = xl[o + ustr];
          xr2 = xl[o + 2 * ustr]; xr3 = xl[o + 3 * ustr];
        }

        // x for step 0 (read at phase top; subsequent steps prefetched)
        v2f xq[4];
        {
          const v2f* s = (const v2f*)&xbuf[buf][0];
          xq[0] = s[0]; xq[1] = s[1]; xq[2] = s[2]; xq[3] = s[3];
        }
        for (int j = 0; j < P_LEN; ++j) {
          const int n = p * P_LEN + j;
          v2f xc0 = xq[0], xc1 = xq[1], xc2 = xq[2], xc3 = xq[3];
          if (j + 1 < P_LEN) {
            const v2f* s = (const v2f*)&xbuf[buf][(j + 1) * C_IN];
            xq[0] = s[0]; xq[1] = s[1]; xq[2] = s[2]; xq[3] = s[3];
          }

          // h broadcast -> SGPRs (no movs: scalar fma reads SGPR directly)
          int hs[H_SZ];
#pragma unroll
          for (int k = 0; k < H_SZ; ++k) hs[k] = H_RL(ha, hb, k);

          float a0 = bs1, a1 = 0.f, a2 = bs2, a3 = 0.f;
#pragma unroll
          for (int k = 0; k < H_SZ; k += 2) {
            a0 = __fmaf_rn(__int_as_float(hs[k]),     whs1[k],     a0);
            a1 = __fmaf_rn(__int_as_float(hs[k + 1]), whs1[k + 1], a1);
            a2 = __fmaf_rn(__int_as_float(hs[k]),     whs2[k],     a2);
            a3 = __fmaf_rn(__int_as_float(hs[k + 1]), whs2[k + 1], a3);
          }
          v2f X1 = zero2(), X2 = zero2();
          X1 = fma2(wxp1[0], xc0, X1);  X2 = fma2(wxp2[0], xc0, X2);
          X1 = fma2(wxp1[1], xc1, X1);  X2 = fma2(wxp2[1], xc1, X2);
          X1 = fma2(wxp1[2], xc2, X1);  X2 = fma2(wxp2[2], xc2, X2);
          X1 = fma2(wxp1[3], xc3, X1);  X2 = fma2(wxp2[3], xc3, X2);

          float G1 = (a0 + a1) + (X1.x + X1.y);
          float G2 = (a2 + a3) + (X2.x + X2.y);
          float act1 = act_s(G1, am, ad);
          float act2 = act_s(G2, am, ad);

          float iv = quad_bcast<0>(act1), fv = quad_bcast<1>(act1);
          float gv = quad_bcast<2>(act1), ov = quad_bcast<3>(act1);
          ca = __fmaf_rn(fv, ca, iv * gv);
          ha = ov * fast_tanh(ca);
          iv = quad_bcast<0>(act2); fv = quad_bcast<1>(act2);
          gv = quad_bcast<2>(act2); ov = quad_bcast<3>(act2);
          cb = __fmaf_rn(fv, cb, iv * gv);
          hb = ov * fast_tanh(cb);

          const int slot = n & (RING - 1);
          if (g == 0) {
            hbuf[slot][k1] = ha;                   // k 0..15
            if (k1 < 4) hbuf[slot][16 + k1] = hb;  // k 16..19
          }
        }
      }
      __syncthreads();   // 65 barriers total, both waves
    }
  } else {
    // ================= layer-1 consumer wave (lags one phase) =================
    v2f   wyp1[H_SZ / 2], wyp2[H_SZ / 2];  // Wih1 rows, k-paired, prescaled
    float wqs1[H_SZ], wqs2[H_SZ];          // Whh1 rows, scalar, prescaled
#pragma unroll
    for (int t = 0; t < H_SZ / 2; ++t) {
      wyp1[t].x = Wih1[j1 * H_SZ + 2 * t] * cm;
      wyp1[t].y = Wih1[j1 * H_SZ + 2 * t + 1] * cm;
      wyp2[t].x = Wih1[j2 * H_SZ + 2 * t] * cm;
      wyp2[t].y = Wih1[j2 * H_SZ + 2 * t + 1] * cm;
    }
#pragma unroll
    for (int k = 0; k < H_SZ; ++k) {
      wqs1[k] = Whh1[j1 * H_SZ + k] * cm;
      wqs2[k] = Whh1[j2 * H_SZ + k] * cm;
    }
    const float bs1 = (bih1[j1] + bhh1[j1]) * cm;
    const float bs2 = (bih1[j2] + bhh1[j2]) * cm;

    float ha = 0.f, hb = 0.f, ca = 0.f, cb = 0.f;
    float* op = out + (size_t)b * H_SZ;

    auto step = [&](const v2f (&y)[H_SZ / 2]) {
      // q = h1 recurrence via readlane SGPRs (critical path)
      int qs[H_SZ];
#pragma unroll
      for (int k = 0; k < H_SZ; ++k) qs[k] = H_RL(ha, hb, k);

      float a0 = bs1, a1 = 0.f, a2 = bs2, a3 = 0.f;
#pragma unroll
      for (int k = 0; k < H_SZ; k += 2) {
        a0 = __fmaf_rn(__int_as_float(qs[k]),     wqs1[k],     a0);
        a1 = __fmaf_rn(__int_as_float(qs[k + 1]), wqs1[k + 1], a1);
        a2 = __fmaf_rn(__int_as_float(qs[k]),     wqs2[k],     a2);
        a3 = __fmaf_rn(__int_as_float(qs[k + 1]), wqs2[k + 1], a3);
      }
      // y = h0(m), LDS-paired, prefetched (off critical path)
      v2f Y1 = zero2(), Y2 = zero2(), Y3 = zero2(), Y4 = zero2();
#pragma unroll
      for (int t = 0; t < H_SZ / 2; t += 2) {
        Y1 = fma2(wyp1[t],     y[t],     Y1);
        Y2 = fma2(wyp2[t],     y[t],     Y2);
        Y3 = fma2(wyp1[t + 1], y[t + 1], Y3);
        Y4 = fma2(wyp2[t + 1], y[t + 1], Y4);
      }
      v2f S1 = Y1 + Y3, S2 = Y2 + Y4;
      float G1 = (a0 + a1) + (S1.x + S1.y);
      float G2 = (a2 + a3) + (S2.x + S2.y);
      float act1 = act_s(G1, am, ad);
      float act2 = act_s(G2, am, ad);

      float iv = quad_bcast<0>(act1), fv = quad_bcast<1>(act1);
      float gv = quad_bcast<2>(act1), ov = quad_bcast<3>(act1);
      ca = __fmaf_rn(fv, ca, iv * gv);
      ha = ov * fast_tanh(ca);
      iv = quad_bcast<0>(act2); fv = quad_bcast<1>(act2);
      gv = quad_bcast<2>(act2); ov = quad_bcast<3>(act2);
      cb = __fmaf_rn(fv, cb, iv * gv);
      hb = ov * fast_tanh(cb);

      if (g == 0) {
        op[k1] = ha;
        if (k1 < 4) op[16 + k1] = hb;
      }
      op += (size_t)B_SZ * H_SZ;
    };

    auto loadY = [&](v2f (&y)[H_SZ / 2], int slot) {
      const v2f* s = (const v2f*)hbuf[slot];
#pragma unroll
      for (int t = 0; t < H_SZ / 2; ++t) y[t] = s[t];
    };

    for (int p = 0; p <= N_PH; ++p) {
      if (p >= 1) {
        const int base = (p - 1) * P_LEN;
        v2f yA[H_SZ / 2], yB[H_SZ / 2];
        loadY(yA, base & (RING - 1));
        loadY(yB, (base + 1) & (RING - 1));
        for (int jj = 0; jj < P_LEN; jj += 2) {
          step(yA);
          if (jj + 2 < P_LEN) loadY(yA, (base + jj + 2) & (RING - 1));
          step(yB);
          if (jj + 3 < P_LEN) loadY(yB, (base + jj + 3) & (RING - 1));
        }
      }
      __syncthreads();
    }
  }
}

} // namespace

extern "C" void kernel_launch(void* const* d_in, const int* in_sizes, int n_in,
                              void* d_out, int out_size, void* d_ws, size_t ws_size,
                              hipStream_t stream) {
  const float* x    = (const float*)d_in[0];
  const float* Wih0 = (const float*)d_in[1];
  const float* Whh0 = (const float*)d_in[2];
  const float* bih0 = (const float*)d_in[3];
  const float* bhh0 = (const float*)d_in[4];
  const float* Wih1 = (const float*)d_in[5];
  const float* Whh1 = (const float*)d_in[6];
  const float* bih1 = (const float*)d_in[7];
  const float* bhh1 = (const float*)d_in[8];
  float* out = (float*)d_out;

  hipLaunchKernelGGL(lstm2_hy, dim3(B_SZ), dim3(128), 0, stream,
                     x, Wih0, Whh0, bih0, bhh0, Wih1, Whh1, bih1, bhh1, out);
}